// Round 4
// baseline (310.481 us; speedup 1.0000x reference)
//
#include <hip/hip_runtime.h>

#define BATCH 8
#define CH 512
#define C16 32
#define W 64
#define HWSZ 4096   // 64*64
#define NCH 4096    // BATCH*CH
#define LDS_STRIDE 68  // 64 + 4 pad

#define NEG_INF (-__builtin_inff())

// ---- Kernel A: per-channel GAP; last block per batch computes the SE score ----
__global__ __launch_bounds__(256) void gap_score_kernel(
        const float* __restrict__ x,
        const float* __restrict__ w1, const float* __restrict__ b1,
        const float* __restrict__ w2, const float* __restrict__ b2,
        float* __restrict__ gap, float* __restrict__ s_out,
        unsigned int* __restrict__ counters) {
    const int chan = blockIdx.x;
    const int bidx = chan >> 9;  // batch
    const float* xp = x + (size_t)chan * HWSZ;
    const int t = threadIdx.x;
    float sum = 0.f;
#pragma unroll
    for (int j = 0; j < 4; ++j) {
        const float4 f = *(const float4*)(xp + t * 4 + j * 1024);
        sum += f.x + f.y + f.z + f.w;
    }
#pragma unroll
    for (int off = 32; off > 0; off >>= 1) sum += __shfl_down(sum, off, 64);
    __shared__ float ws[4];
    __shared__ int is_last;
    if ((t & 63) == 0) ws[t >> 6] = sum;
    __syncthreads();
    if (t == 0) {
        const float mean = (ws[0] + ws[1] + ws[2] + ws[3]) * (1.0f / HWSZ);
        // agent-scope release store -> visible device-wide once the counter
        // increment below is observed (standard release/acquire chain).
        __hip_atomic_store(&gap[chan], mean, __ATOMIC_RELEASE, __HIP_MEMORY_SCOPE_AGENT);
        const unsigned old = __hip_atomic_fetch_add(&counters[bidx], 1u,
                                                    __ATOMIC_ACQ_REL, __HIP_MEMORY_SCOPE_AGENT);
        is_last = (old == (unsigned)(CH - 1));
    }
    __syncthreads();
    if (!is_last) return;

    // ---- last block of this batch: compute scores for all 512 channels ----
    __shared__ float g[CH];
    __shared__ float partial[C16][9];  // +1 pad
    __shared__ float hmid[C16];
    g[t]       = __hip_atomic_load(&gap[bidx * CH + t],       __ATOMIC_RELAXED, __HIP_MEMORY_SCOPE_AGENT);
    g[t + 256] = __hip_atomic_load(&gap[bidx * CH + t + 256], __ATOMIC_RELAXED, __HIP_MEMORY_SCOPE_AGENT);
    __syncthreads();
    {
        const int e = t >> 3, part = t & 7;
        float p = 0.f;
        const int j0 = part * 64;
        for (int j = 0; j < 64; ++j) p += g[j0 + j] * w1[e * CH + j0 + j];
        partial[e][part] = p;
    }
    __syncthreads();
    if (t < C16) {
        float acc = b1[t];
#pragma unroll
        for (int j = 0; j < 8; ++j) acc += partial[t][j];
        hmid[t] = fmaxf(acc, 0.f);
    }
    __syncthreads();
#pragma unroll
    for (int ci = 0; ci < 2; ++ci) {
        const int c = t + ci * 256;
        float acc = b2[c];
#pragma unroll
        for (int e2 = 0; e2 < C16; ++e2) acc += hmid[e2] * w2[c * C16 + e2];
        s_out[bidx * CH + c] = fmaxf(acc, 0.f);  // expend_num_relu
    }
}

// ---------------- Kernel B: routed dual maxpool + blend + residual ----------------
__device__ __forceinline__ float4 max4(float4 a, float4 b) {
    return make_float4(fmaxf(a.x, b.x), fmaxf(a.y, b.y), fmaxf(a.z, b.z), fmaxf(a.w, b.w));
}
__device__ __forceinline__ float max3f(float a, float b, float c) {
    return fmaxf(fmaxf(a, b), c);  // clang folds to v_max3_f32
}

// level needed for half-width h: smallest L with 2^L >= h+1
constexpr int lvl(int h) { return h <= 0 ? 0 : (h <= 1 ? 1 : (h <= 3 ? 2 : 3)); }

// Horizontal: v[32] covers row positions [seg*16-8, seg*16+24); outputs 16 px
// of the half-Q window max ONLY (the Q+1 plane is derived in phase 2 by dilation).
template <int Q>
__device__ __forceinline__ void hpool_s(const float v[32], float os[16]) {
    constexpr int LS = lvl(Q);
    float m2[31], m4[29], m8[25];
    if constexpr (LS >= 1) {
#pragma unroll
        for (int j = 0; j < 31; ++j) m2[j] = fmaxf(v[j], v[j + 1]);
    }
    if constexpr (LS >= 2) {
#pragma unroll
        for (int j = 0; j < 29; ++j) m4[j] = fmaxf(m2[j], m2[j + 2]);
    }
    if constexpr (LS >= 3) {
#pragma unroll
        for (int j = 0; j < 25; ++j) m8[j] = fmaxf(m4[j], m4[j + 4]);
    }
#pragma unroll
    for (int i = 0; i < 16; ++i) {
        const int pos = 8 + i;
        constexpr int P = 1 << LS;
        const int a = pos - Q, b = pos + Q - P + 1;
        if constexpr (LS == 0) os[i] = v[pos];
        else if constexpr (LS == 1) os[i] = fmaxf(m2[a], m2[b]);
        else if constexpr (LS == 2) os[i] = fmaxf(m4[a], m4[b]);
        else os[i] = fmaxf(m8[a], m8[b]);
    }
}

// Vertical over hs rows, SHARED pyramid: v[16] covers rows [y0-6, y0+9].
// os4 = vertical half-Q max (s branch, final).
// pre4 = vertical half-(Q+1) max of the UNdilated hs columns (b branch gets a
//        final horizontal +-1 dilation after this — dilation commutes with max).
template <int Q>
__device__ __forceinline__ void vcomb2(const float4 v[16], float4 os4[4], float4 pre4[4]) {
    constexpr int LS = lvl(Q);
    constexpr int LB = lvl(Q + 1);  // LB >= LS always
    float4 m2[15], m4[13], m8[9];
    if constexpr (LB >= 1) {
#pragma unroll
        for (int j = 0; j < 15; ++j) m2[j] = max4(v[j], v[j + 1]);
    }
    if constexpr (LB >= 2) {
#pragma unroll
        for (int j = 0; j < 13; ++j) m4[j] = max4(m2[j], m2[j + 2]);
    }
    if constexpr (LB >= 3) {
#pragma unroll
        for (int j = 0; j < 9; ++j) m8[j] = max4(m4[j], m4[j + 4]);
    }
#pragma unroll
    for (int i = 0; i < 4; ++i) {
        const int pos = 6 + i;
        {   // s branch: half Q at level LS
            constexpr int P = 1 << LS;
            const int a = pos - Q, b = pos + Q - P + 1;
            if constexpr (LS == 0) os4[i] = v[pos];
            else if constexpr (LS == 1) os4[i] = max4(m2[a], m2[b]);
            else if constexpr (LS == 2) os4[i] = max4(m4[a], m4[b]);
            else os4[i] = max4(m8[a], m8[b]);
        }
        {   // b branch pre: half Q+1 at level LB (same pyramid!)
            constexpr int HH = Q + 1;
            constexpr int P = 1 << LB;
            const int a = pos - HH, b = pos + HH - P + 1;
            if constexpr (LB == 1) pre4[i] = max4(m2[a], m2[b]);
            else if constexpr (LB == 2) pre4[i] = max4(m4[a], m4[b]);
            else pre4[i] = max4(m8[a], m8[b]);
        }
    }
}

template <int Q>
__device__ __forceinline__ void pool_body(const float v[32], float* hs,
                                          const float* __restrict__ xp,
                                          float* __restrict__ op, float fb, float fs) {
    const int t = threadIdx.x;
    const int r = t >> 2, seg = t & 3;
    float os[16];
    hpool_s<Q>(v, os);
    float* hsp = hs + r * LDS_STRIDE + seg * 16;
#pragma unroll
    for (int j = 0; j < 4; ++j) {
        *(float4*)(hsp + 4 * j) = make_float4(os[4*j], os[4*j+1], os[4*j+2], os[4*j+3]);
    }
    __syncthreads();
    const int cg = t & 15, rb = t >> 4;
    const int x0 = cg * 4, y0 = rb * 4;
    // issue residual loads FIRST: global latency hides under LDS reads + pyramid
    float4 xv[4];
#pragma unroll
    for (int i = 0; i < 4; ++i) {
        xv[i] = *(const float4*)(xp + (y0 + i) * W + x0);
    }
    float4 av[16];
#pragma unroll
    for (int j = 0; j < 16; ++j) {
        int row = y0 - 6 + j;
        row = row < 0 ? 0 : (row > 63 ? 63 : row);  // clamp == SAME pad for max
        av[j] = *(const float4*)(hs + row * LDS_STRIDE + x0);
    }
    float4 vs4[4], pre4[4];
    vcomb2<Q>(av, vs4, pre4);
#pragma unroll
    for (int i = 0; i < 4; ++i) {
        const float4 pre = pre4[i];
        // horizontal +-1 dilation: neighbor columns come from adjacent lanes.
        float lp = __shfl_up(pre.w, 1);    // col x0-1 (left lane's .w)
        float rp = __shfl_down(pre.x, 1);  // col x0+4 (right lane's .x)
        if (cg == 0) lp = pre.x;           // clamp at image edge (SAME pad)
        if (cg == 15) rp = pre.w;
        float4 vb;
        vb.x = max3f(lp,    pre.x, pre.y);
        vb.y = max3f(pre.x, pre.y, pre.z);
        vb.z = max3f(pre.y, pre.z, pre.w);
        vb.w = max3f(pre.z, pre.w, rp);
        float4 o;
        o.x = fb * vb.x + fs * vs4[i].x + xv[i].x;
        o.y = fb * vb.y + fs * vs4[i].y + xv[i].y;
        o.z = fb * vb.z + fs * vs4[i].z + xv[i].z;
        o.w = fb * vb.w + fs * vs4[i].w + xv[i].w;
        *(float4*)(op + (y0 + i) * W + x0) = o;
    }
}

__global__ __launch_bounds__(256) void pool_kernel(const float* __restrict__ x,
                                                   const float* __restrict__ s_arr,
                                                   float* __restrict__ out) {
    __shared__ float hs[64 * LDS_STRIDE];  // 17,408 B
    const int chan = blockIdx.x;  // block-uniform routing -> no divergence
    const float* xp = x + (size_t)chan * HWSZ;
    float* op = out + (size_t)chan * HWSZ;
    const float s = s_arr[chan];
    int q = (int)floorf(s);
    q = q < 0 ? 0 : (q > 5 ? 5 : q);
    const float fb = s - (float)q;        // weight on larger kernel
    const float fs = (float)(q + 1) - s;  // weight on smaller kernel

    const int t = threadIdx.x;
    const int r = t >> 2, seg = t & 3;
    float v[32];
    const float* rowp = xp + r * W;
#pragma unroll
    for (int j = 0; j < 8; ++j) {
        const int p = seg * 16 - 8 + j * 4;
        if (p >= 0 && p < W) {
            const float4 f = *(const float4*)(rowp + p);
            v[4*j] = f.x; v[4*j+1] = f.y; v[4*j+2] = f.z; v[4*j+3] = f.w;
        } else {
            v[4*j] = NEG_INF; v[4*j+1] = NEG_INF; v[4*j+2] = NEG_INF; v[4*j+3] = NEG_INF;
        }
    }
    switch (q) {
        case 0: pool_body<0>(v, hs, xp, op, fb, fs); break;
        case 1: pool_body<1>(v, hs, xp, op, fb, fs); break;
        case 2: pool_body<2>(v, hs, xp, op, fb, fs); break;
        case 3: pool_body<3>(v, hs, xp, op, fb, fs); break;
        case 4: pool_body<4>(v, hs, xp, op, fb, fs); break;
        default: pool_body<5>(v, hs, xp, op, fb, fs); break;
    }
}

extern "C" void kernel_launch(void* const* d_in, const int* in_sizes, int n_in,
                              void* d_out, int out_size, void* d_ws, size_t ws_size,
                              hipStream_t stream) {
    const float* x  = (const float*)d_in[0];
    const float* w1 = (const float*)d_in[1];
    const float* b1 = (const float*)d_in[2];
    const float* w2 = (const float*)d_in[3];
    const float* b2 = (const float*)d_in[4];
    float* out = (float*)d_out;
    float* gap = (float*)d_ws;                         // NCH floats
    float* s   = (float*)d_ws + NCH;                   // NCH floats
    unsigned int* counters = (unsigned int*)((float*)d_ws + 2 * NCH);  // BATCH uints

    // workspace is re-poisoned by the harness each iteration -> zero the counters
    hipMemsetAsync(counters, 0, BATCH * sizeof(unsigned int), stream);
    gap_score_kernel<<<NCH, 256, 0, stream>>>(x, w1, b1, w2, b2, gap, s, counters);
    pool_kernel<<<NCH, 256, 0, stream>>>(x, s, out);
}

// Round 5
// 138.746 us; speedup vs baseline: 2.2378x; 2.2378x over previous
//
#include <hip/hip_runtime.h>

#define BATCH 8
#define CH 512
#define C16 32
#define W 64
#define HWSZ 4096   // 64*64
#define NCH 4096    // BATCH*CH
#define LDS_STRIDE 68  // 64 + 4 pad

#define NEG_INF (-__builtin_inff())

// ---------------- Kernel A: per-channel global average pool ----------------
__global__ __launch_bounds__(256) void gap_kernel(const float* __restrict__ x,
                                                  float* __restrict__ gap) {
    const int chan = blockIdx.x;
    const float* xp = x + (size_t)chan * HWSZ;
    const int t = threadIdx.x;
    float sum = 0.f;
#pragma unroll
    for (int j = 0; j < 4; ++j) {
        const float4 f = *(const float4*)(xp + t * 4 + j * 1024);
        sum += f.x + f.y + f.z + f.w;
    }
#pragma unroll
    for (int off = 32; off > 0; off >>= 1) sum += __shfl_down(sum, off, 64);
    __shared__ float ws[4];
    if ((t & 63) == 0) ws[t >> 6] = sum;
    __syncthreads();
    if (t == 0) {
        gap[chan] = (ws[0] + ws[1] + ws[2] + ws[3]) * (1.0f / HWSZ);
    }
}

// ---------------- Kernel B: SE bottleneck -> routing score s ----------------
__global__ __launch_bounds__(256) void score_kernel(const float* __restrict__ gap,
                                                    const float* __restrict__ w1,
                                                    const float* __restrict__ b1,
                                                    const float* __restrict__ w2,
                                                    const float* __restrict__ b2,
                                                    float* __restrict__ s_out) {
    const int b = blockIdx.x;   // one block per batch
    const int t = threadIdx.x;
    __shared__ float g[CH];
    __shared__ float partial[C16][9];  // +1 pad
    __shared__ float hmid[C16];
    g[t] = gap[b * CH + t];
    g[t + 256] = gap[b * CH + t + 256];
    __syncthreads();
    const int e = t >> 3, part = t & 7;
    float p = 0.f;
    const int j0 = part * 64;
    for (int j = 0; j < 64; ++j) p += g[j0 + j] * w1[e * CH + j0 + j];
    partial[e][part] = p;
    __syncthreads();
    if (t < C16) {
        float acc = b1[t];
#pragma unroll
        for (int j = 0; j < 8; ++j) acc += partial[t][j];
        hmid[t] = fmaxf(acc, 0.f);
    }
    __syncthreads();
#pragma unroll
    for (int ci = 0; ci < 2; ++ci) {
        const int c = t + ci * 256;
        float acc = b2[c];
#pragma unroll
        for (int e2 = 0; e2 < C16; ++e2) acc += hmid[e2] * w2[c * C16 + e2];
        s_out[b * CH + c] = fmaxf(acc, 0.f);  // expend_num_relu
    }
}

// ---------------- Kernel C: routed dual maxpool, 2-channel pipelined ----------------
__device__ __forceinline__ float4 max4(float4 a, float4 b) {
    return make_float4(fmaxf(a.x, b.x), fmaxf(a.y, b.y), fmaxf(a.z, b.z), fmaxf(a.w, b.w));
}
__device__ __forceinline__ float max3f(float a, float b, float c) {
    return fmaxf(fmaxf(a, b), c);  // clang folds to v_max3_f32
}

// level needed for half-width h: smallest L with 2^L >= h+1
constexpr int lvl(int h) { return h <= 0 ? 0 : (h <= 1 ? 1 : (h <= 3 ? 2 : 3)); }

// Horizontal: v[32] covers row positions [seg*16-8, seg*16+24); outputs 16 px
// of the half-Q window max (the Q+1 plane is derived in phase 2 by dilation).
template <int Q>
__device__ __forceinline__ void hpool_s(const float v[32], float os[16]) {
    constexpr int LS = lvl(Q);
    float m2[31], m4[29], m8[25];
    if constexpr (LS >= 1) {
#pragma unroll
        for (int j = 0; j < 31; ++j) m2[j] = fmaxf(v[j], v[j + 1]);
    }
    if constexpr (LS >= 2) {
#pragma unroll
        for (int j = 0; j < 29; ++j) m4[j] = fmaxf(m2[j], m2[j + 2]);
    }
    if constexpr (LS >= 3) {
#pragma unroll
        for (int j = 0; j < 25; ++j) m8[j] = fmaxf(m4[j], m4[j + 4]);
    }
#pragma unroll
    for (int i = 0; i < 16; ++i) {
        const int pos = 8 + i;
        constexpr int P = 1 << LS;
        const int a = pos - Q, b = pos + Q - P + 1;
        if constexpr (LS == 0) os[i] = v[pos];
        else if constexpr (LS == 1) os[i] = fmaxf(m2[a], m2[b]);
        else if constexpr (LS == 2) os[i] = fmaxf(m4[a], m4[b]);
        else os[i] = fmaxf(m8[a], m8[b]);
    }
}

// Phase 1: horizontal pool into the shared hs plane.
template <int Q>
__device__ __forceinline__ void phase1(const float v[32], float* hs, int r, int seg) {
    float os[16];
    hpool_s<Q>(v, os);
    float* hsp = hs + r * LDS_STRIDE + seg * 16;
#pragma unroll
    for (int j = 0; j < 4; ++j) {
        *(float4*)(hsp + 4 * j) = make_float4(os[4*j], os[4*j+1], os[4*j+2], os[4*j+3]);
    }
}

// Phase 2: LDS reads + shared vertical pyramid.
// vs4 = final s-branch values; pre4 = b-branch before horizontal +-1 dilation
// (dilation commutes with the vertical max).
template <int Q>
__device__ __forceinline__ void phase2(const float* hs, int x0, int y0,
                                       float4 vs4[4], float4 pre4[4]) {
    constexpr int LS = lvl(Q);
    constexpr int LB = lvl(Q + 1);  // LB >= LS always
    float4 v[16];
#pragma unroll
    for (int j = 0; j < 16; ++j) {
        int row = y0 - 6 + j;
        row = row < 0 ? 0 : (row > 63 ? 63 : row);  // clamp == SAME pad for max
        v[j] = *(const float4*)(hs + row * LDS_STRIDE + x0);
    }
    float4 m2[15], m4[13], m8[9];
    if constexpr (LB >= 1) {
#pragma unroll
        for (int j = 0; j < 15; ++j) m2[j] = max4(v[j], v[j + 1]);
    }
    if constexpr (LB >= 2) {
#pragma unroll
        for (int j = 0; j < 13; ++j) m4[j] = max4(m2[j], m2[j + 2]);
    }
    if constexpr (LB >= 3) {
#pragma unroll
        for (int j = 0; j < 9; ++j) m8[j] = max4(m4[j], m4[j + 4]);
    }
#pragma unroll
    for (int i = 0; i < 4; ++i) {
        const int pos = 6 + i;
        {   // s branch: half Q at level LS
            constexpr int P = 1 << LS;
            const int a = pos - Q, b = pos + Q - P + 1;
            if constexpr (LS == 0) vs4[i] = v[pos];
            else if constexpr (LS == 1) vs4[i] = max4(m2[a], m2[b]);
            else if constexpr (LS == 2) vs4[i] = max4(m4[a], m4[b]);
            else vs4[i] = max4(m8[a], m8[b]);
        }
        {   // b branch pre: half Q+1 at level LB (same pyramid!)
            constexpr int HH = Q + 1;
            constexpr int P = 1 << LB;
            const int a = pos - HH, b = pos + HH - P + 1;
            if constexpr (LB == 1) pre4[i] = max4(m2[a], m2[b]);
            else if constexpr (LB == 2) pre4[i] = max4(m4[a], m4[b]);
            else pre4[i] = max4(m8[a], m8[b]);
        }
    }
}

// Q-independent epilogue: horizontal +-1 dilation of pre4 via lane shuffles,
// bilinear blend, residual add, store.
__device__ __forceinline__ void dilate_store(const float4 vs4[4], const float4 pre4[4],
                                             const float4 xv[4], float fb, float fs,
                                             float* __restrict__ op, int cg, int x0, int y0) {
#pragma unroll
    for (int i = 0; i < 4; ++i) {
        const float4 pre = pre4[i];
        float lp = __shfl_up(pre.w, 1);    // col x0-1 (left lane's .w)
        float rp = __shfl_down(pre.x, 1);  // col x0+4 (right lane's .x)
        if (cg == 0) lp = pre.x;           // clamp at image edge (SAME pad)
        if (cg == 15) rp = pre.w;
        float4 vb;
        vb.x = max3f(lp,    pre.x, pre.y);
        vb.y = max3f(pre.x, pre.y, pre.z);
        vb.z = max3f(pre.y, pre.z, pre.w);
        vb.w = max3f(pre.z, pre.w, rp);
        float4 o;
        o.x = fb * vb.x + fs * vs4[i].x + xv[i].x;
        o.y = fb * vb.y + fs * vs4[i].y + xv[i].y;
        o.z = fb * vb.z + fs * vs4[i].z + xv[i].z;
        o.w = fb * vb.w + fs * vs4[i].w + xv[i].w;
        *(float4*)(op + (y0 + i) * W + x0) = o;
    }
}

__device__ __forceinline__ void load_window(const float* __restrict__ rowp, int seg,
                                            float v[32]) {
#pragma unroll
    for (int j = 0; j < 8; ++j) {
        const int p = seg * 16 - 8 + j * 4;
        if (p >= 0 && p < W) {
            const float4 f = *(const float4*)(rowp + p);
            v[4*j] = f.x; v[4*j+1] = f.y; v[4*j+2] = f.z; v[4*j+3] = f.w;
        } else {
            v[4*j] = NEG_INF; v[4*j+1] = NEG_INF; v[4*j+2] = NEG_INF; v[4*j+3] = NEG_INF;
        }
    }
}

__device__ __forceinline__ void mk_route(float s, int& q, float& fb, float& fs) {
    q = (int)floorf(s);
    q = q < 0 ? 0 : (q > 5 ? 5 : q);
    fb = s - (float)q;        // weight on larger kernel
    fs = (float)(q + 1) - s;  // weight on smaller kernel
}

#define P1(QV, VREG) case QV: phase1<QV>(VREG, hs, r, seg); break;
#define P2(QV, VS, PRE) case QV: phase2<QV>(hs, x0, y0, VS, PRE); break;

// One block = two consecutive channels (same routing pipeline, shared LDS plane).
// Schedule: [loadA, hp1A] bar [loadB+xvA issue, ph2A] bar [hp1B, storeA] bar [ph2B, storeB]
// -> B's global latency hides under A's pyramid; A's stores hide under B's LDS writes.
__global__ __launch_bounds__(256) void pool_kernel(const float* __restrict__ x,
                                                   const float* __restrict__ s_arr,
                                                   float* __restrict__ out) {
    __shared__ float hs[64 * LDS_STRIDE];  // 17,408 B
    const int pair = blockIdx.x;           // 0..2047
    const int cA = pair * 2, cB = cA + 1;
    const float* xpA = x + (size_t)cA * HWSZ;
    const float* xpB = x + (size_t)cB * HWSZ;
    float* opA = out + (size_t)cA * HWSZ;
    float* opB = out + (size_t)cB * HWSZ;

    int qA, qB; float fbA, fsA, fbB, fsB;
    mk_route(s_arr[cA], qA, fbA, fsA);     // block-uniform -> no divergence
    mk_route(s_arr[cB], qB, fbB, fsB);

    const int t = threadIdx.x;
    const int r = t >> 2, seg = t & 3;
    const int cg = t & 15, rb = t >> 4;
    const int x0 = cg * 4, y0 = rb * 4;

    // ---- stage 1: channel A horizontal ----
    float vA[32];
    load_window(xpA + r * W, seg, vA);
    switch (qA) { P1(0, vA) P1(1, vA) P1(2, vA) P1(3, vA) P1(4, vA) default: phase1<5>(vA, hs, r, seg); }
    __syncthreads();

    // ---- stage 2: channel A vertical; B's window + A's residual loads in flight ----
    float vB[32];
    load_window(xpB + r * W, seg, vB);
    float4 xvA[4];
#pragma unroll
    for (int i = 0; i < 4; ++i) xvA[i] = *(const float4*)(xpA + (y0 + i) * W + x0);
    float4 vs4A[4], pre4A[4];
    switch (qA) { P2(0, vs4A, pre4A) P2(1, vs4A, pre4A) P2(2, vs4A, pre4A)
                  P2(3, vs4A, pre4A) P2(4, vs4A, pre4A) default: phase2<5>(hs, x0, y0, vs4A, pre4A); }
    __syncthreads();   // A's LDS reads done -> plane reusable; drains vB/xvA

    // ---- stage 3: channel B horizontal; A epilogue overlaps B's LDS writes ----
    switch (qB) { P1(0, vB) P1(1, vB) P1(2, vB) P1(3, vB) P1(4, vB) default: phase1<5>(vB, hs, r, seg); }
    dilate_store(vs4A, pre4A, xvA, fbA, fsA, opA, cg, x0, y0);
    __syncthreads();

    // ---- stage 4: channel B vertical + epilogue ----
    float4 xvB[4];
#pragma unroll
    for (int i = 0; i < 4; ++i) xvB[i] = *(const float4*)(xpB + (y0 + i) * W + x0);
    float4 vs4B[4], pre4B[4];
    switch (qB) { P2(0, vs4B, pre4B) P2(1, vs4B, pre4B) P2(2, vs4B, pre4B)
                  P2(3, vs4B, pre4B) P2(4, vs4B, pre4B) default: phase2<5>(hs, x0, y0, vs4B, pre4B); }
    dilate_store(vs4B, pre4B, xvB, fbB, fsB, opB, cg, x0, y0);
}

extern "C" void kernel_launch(void* const* d_in, const int* in_sizes, int n_in,
                              void* d_out, int out_size, void* d_ws, size_t ws_size,
                              hipStream_t stream) {
    const float* x  = (const float*)d_in[0];
    const float* w1 = (const float*)d_in[1];
    const float* b1 = (const float*)d_in[2];
    const float* w2 = (const float*)d_in[3];
    const float* b2 = (const float*)d_in[4];
    float* out = (float*)d_out;
    float* gap = (float*)d_ws;                 // NCH floats
    float* s   = (float*)d_ws + NCH;           // NCH floats

    gap_kernel<<<NCH, 256, 0, stream>>>(x, gap);
    score_kernel<<<BATCH, 256, 0, stream>>>(gap, w1, b1, w2, b2, s);
    pool_kernel<<<NCH / 2, 256, 0, stream>>>(x, s, out);
}

// Round 6
// 132.846 us; speedup vs baseline: 2.3372x; 1.0444x over previous
//
#include <hip/hip_runtime.h>

#define BATCH 8
#define CH 512
#define C16 32
#define W 64
#define HWSZ 4096   // 64*64
#define NCH 4096    // BATCH*CH
#define LDS_STRIDE 68  // 64 + 4 pad
#define CPB 4          // channels per block in fused kernel
#define NBLK (NCH / CPB)

#define NEG_INF (-__builtin_inff())

// ---------------- Kernel A: per-channel global average pool ----------------
__global__ __launch_bounds__(256) void gap_kernel(const float* __restrict__ x,
                                                  float* __restrict__ gap) {
    const int chan = blockIdx.x;
    const float* xp = x + (size_t)chan * HWSZ;
    const int t = threadIdx.x;
    float sum = 0.f;
#pragma unroll
    for (int j = 0; j < 4; ++j) {
        const float4 f = *(const float4*)(xp + t * 4 + j * 1024);
        sum += f.x + f.y + f.z + f.w;
    }
#pragma unroll
    for (int off = 32; off > 0; off >>= 1) sum += __shfl_down(sum, off, 64);
    __shared__ float ws[4];
    if ((t & 63) == 0) ws[t >> 6] = sum;
    __syncthreads();
    if (t == 0) {
        gap[chan] = (ws[0] + ws[1] + ws[2] + ws[3]) * (1.0f / HWSZ);
    }
}

// ---------------- Kernel B: fused SE-score + routed dual maxpool ----------------
__device__ __forceinline__ float4 max4(float4 a, float4 b) {
    return make_float4(fmaxf(a.x, b.x), fmaxf(a.y, b.y), fmaxf(a.z, b.z), fmaxf(a.w, b.w));
}
__device__ __forceinline__ float max3f(float a, float b, float c) {
    return fmaxf(fmaxf(a, b), c);  // clang folds to v_max3_f32
}

// level needed for half-width h: smallest L with 2^L >= h+1
constexpr int lvl(int h) { return h <= 0 ? 0 : (h <= 1 ? 1 : (h <= 3 ? 2 : 3)); }

// Horizontal: v[32] covers row positions [seg*16-8, seg*16+24); outputs 16 px
// of the half-Q window max (the Q+1 plane is derived in phase 2 by dilation).
template <int Q>
__device__ __forceinline__ void hpool_s(const float v[32], float os[16]) {
    constexpr int LS = lvl(Q);
    float m2[31], m4[29], m8[25];
    if constexpr (LS >= 1) {
#pragma unroll
        for (int j = 0; j < 31; ++j) m2[j] = fmaxf(v[j], v[j + 1]);
    }
    if constexpr (LS >= 2) {
#pragma unroll
        for (int j = 0; j < 29; ++j) m4[j] = fmaxf(m2[j], m2[j + 2]);
    }
    if constexpr (LS >= 3) {
#pragma unroll
        for (int j = 0; j < 25; ++j) m8[j] = fmaxf(m4[j], m4[j + 4]);
    }
#pragma unroll
    for (int i = 0; i < 16; ++i) {
        const int pos = 8 + i;
        constexpr int P = 1 << LS;
        const int a = pos - Q, b = pos + Q - P + 1;
        if constexpr (LS == 0) os[i] = v[pos];
        else if constexpr (LS == 1) os[i] = fmaxf(m2[a], m2[b]);
        else if constexpr (LS == 2) os[i] = fmaxf(m4[a], m4[b]);
        else os[i] = fmaxf(m8[a], m8[b]);
    }
}

// Phase 1: horizontal pool into the shared hs plane.
template <int Q>
__device__ __forceinline__ void phase1(const float v[32], float* hs, int r, int seg) {
    float os[16];
    hpool_s<Q>(v, os);
    float* hsp = hs + r * LDS_STRIDE + seg * 16;
#pragma unroll
    for (int j = 0; j < 4; ++j) {
        *(float4*)(hsp + 4 * j) = make_float4(os[4*j], os[4*j+1], os[4*j+2], os[4*j+3]);
    }
}

// Phase 2: LDS reads + shared vertical pyramid.
// vs4 = final s-branch values; pre4 = b-branch before horizontal +-1 dilation
// (dilation commutes with the vertical max).
template <int Q>
__device__ __forceinline__ void phase2(const float* hs, int x0, int y0,
                                       float4 vs4[4], float4 pre4[4]) {
    constexpr int LS = lvl(Q);
    constexpr int LB = lvl(Q + 1);  // LB >= LS always
    float4 v[16];
#pragma unroll
    for (int j = 0; j < 16; ++j) {
        int row = y0 - 6 + j;
        row = row < 0 ? 0 : (row > 63 ? 63 : row);  // clamp == SAME pad for max
        v[j] = *(const float4*)(hs + row * LDS_STRIDE + x0);
    }
    float4 m2[15], m4[13], m8[9];
    if constexpr (LB >= 1) {
#pragma unroll
        for (int j = 0; j < 15; ++j) m2[j] = max4(v[j], v[j + 1]);
    }
    if constexpr (LB >= 2) {
#pragma unroll
        for (int j = 0; j < 13; ++j) m4[j] = max4(m2[j], m2[j + 2]);
    }
    if constexpr (LB >= 3) {
#pragma unroll
        for (int j = 0; j < 9; ++j) m8[j] = max4(m4[j], m4[j + 4]);
    }
#pragma unroll
    for (int i = 0; i < 4; ++i) {
        const int pos = 6 + i;
        {   // s branch: half Q at level LS
            constexpr int P = 1 << LS;
            const int a = pos - Q, b = pos + Q - P + 1;
            if constexpr (LS == 0) vs4[i] = v[pos];
            else if constexpr (LS == 1) vs4[i] = max4(m2[a], m2[b]);
            else if constexpr (LS == 2) vs4[i] = max4(m4[a], m4[b]);
            else vs4[i] = max4(m8[a], m8[b]);
        }
        {   // b branch pre: half Q+1 at level LB (same pyramid!)
            constexpr int HH = Q + 1;
            constexpr int P = 1 << LB;
            const int a = pos - HH, b = pos + HH - P + 1;
            if constexpr (LB == 1) pre4[i] = max4(m2[a], m2[b]);
            else if constexpr (LB == 2) pre4[i] = max4(m4[a], m4[b]);
            else pre4[i] = max4(m8[a], m8[b]);
        }
    }
}

// Q-independent epilogue: horizontal +-1 dilation of pre4 via lane shuffles,
// bilinear blend, residual add, store.
__device__ __forceinline__ void dilate_store(const float4 vs4[4], const float4 pre4[4],
                                             const float4 xv[4], float fb, float fs,
                                             float* __restrict__ op, int cg, int x0, int y0) {
#pragma unroll
    for (int i = 0; i < 4; ++i) {
        const float4 pre = pre4[i];
        float lp = __shfl_up(pre.w, 1);    // col x0-1 (left lane's .w)
        float rp = __shfl_down(pre.x, 1);  // col x0+4 (right lane's .x)
        if (cg == 0) lp = pre.x;           // clamp at image edge (SAME pad)
        if (cg == 15) rp = pre.w;
        float4 vb;
        vb.x = max3f(lp,    pre.x, pre.y);
        vb.y = max3f(pre.x, pre.y, pre.z);
        vb.z = max3f(pre.y, pre.z, pre.w);
        vb.w = max3f(pre.z, pre.w, rp);
        float4 o;
        o.x = fb * vb.x + fs * vs4[i].x + xv[i].x;
        o.y = fb * vb.y + fs * vs4[i].y + xv[i].y;
        o.z = fb * vb.z + fs * vs4[i].z + xv[i].z;
        o.w = fb * vb.w + fs * vs4[i].w + xv[i].w;
        *(float4*)(op + (y0 + i) * W + x0) = o;
    }
}

__device__ __forceinline__ void load_window(const float* __restrict__ rowp, int seg,
                                            float v[32]) {
#pragma unroll
    for (int j = 0; j < 8; ++j) {
        const int p = seg * 16 - 8 + j * 4;
        if (p >= 0 && p < W) {
            const float4 f = *(const float4*)(rowp + p);
            v[4*j] = f.x; v[4*j+1] = f.y; v[4*j+2] = f.z; v[4*j+3] = f.w;
        } else {
            v[4*j] = NEG_INF; v[4*j+1] = NEG_INF; v[4*j+2] = NEG_INF; v[4*j+3] = NEG_INF;
        }
    }
}

#define P1(QV) case QV: phase1<QV>(v, hs, r, seg); break;
#define P2(QV) case QV: phase2<QV>(hs, x0, y0, vs4, pre4); break;

// One block = CPB consecutive channels (all in the same batch since CPB | CH).
// Score phase is recomputed per block from gap (conflict-free, coalesced w1):
// only hmid[32] is a true cross-channel dependency; per-channel s is 32 FMAs.
__global__ __launch_bounds__(256, 4) void score_pool_kernel(
        const float* __restrict__ x,
        const float* __restrict__ gap,
        const float* __restrict__ w1, const float* __restrict__ b1,
        const float* __restrict__ w2, const float* __restrict__ b2,
        float* __restrict__ out) {
    __shared__ float hs[64 * LDS_STRIDE];  // 17,408 B
    __shared__ float g[CH];
    __shared__ float partial[C16][9];      // +1 pad (bank-spread: addr=9e+l, gcd(9,32)=1)
    __shared__ float hmid[C16];

    const int c0   = blockIdx.x * CPB;     // first global channel of this block
    const int bidx = c0 >> 9;              // batch
    const int cch0 = c0 & 511;             // first channel within batch
    const int t = threadIdx.x;

    // ---- score phase: hmid = relu(w1 . gap + b1), conflict-free banking ----
    g[t]       = gap[bidx * CH + t];
    g[t + 256] = gap[bidx * CH + t + 256];
    __syncthreads();
    {
        // e = output row (0..31), l = 8-way partial lane. LDS reads g[l+8k]:
        // 8 distinct CONSECUTIVE addresses per wave -> distinct banks, 8-lane
        // broadcast each -> conflict-free. w1 reads: 8 lanes x 32 B contiguous.
        const int e = t >> 3, l = t & 7;
        const float* w1p = w1 + e * CH + l;
        float p = 0.f;
#pragma unroll
        for (int k = 0; k < 64; ++k) p += g[l + 8 * k] * w1p[8 * k];
        partial[e][l] = p;
    }
    __syncthreads();
    if (t < C16) {
        float acc = b1[t];
#pragma unroll
        for (int j = 0; j < 8; ++j) acc += partial[t][j];
        hmid[t] = fmaxf(acc, 0.f);
    }
    __syncthreads();

    const int r = t >> 2, seg = t & 3;
    const int cg = t & 15, rb = t >> 4;
    const int x0 = cg * 4, y0 = rb * 4;

    // ---- pool phase: CPB channels sequential through the shared hs plane ----
    for (int ci = 0; ci < CPB; ++ci) {
        const int chan = c0 + ci;
        const float* xp = x + (size_t)chan * HWSZ;
        float* op = out + (size_t)chan * HWSZ;

        // issue window loads first; s-compute (uniform scalar ops) overlaps
        float v[32];
        load_window(xp + r * W, seg, v);

        // per-channel score from LDS-resident hmid (block-uniform -> scalar)
        const int c = cch0 + ci;
        float sacc = b2[c];
#pragma unroll
        for (int e2 = 0; e2 < C16; ++e2) sacc += hmid[e2] * w2[c * C16 + e2];
        const float s = fmaxf(sacc, 0.f);  // expend_num_relu
        int q = (int)floorf(s);
        q = q < 0 ? 0 : (q > 5 ? 5 : q);
        const float fb = s - (float)q;        // weight on larger kernel
        const float fs = (float)(q + 1) - s;  // weight on smaller kernel

        switch (q) { P1(0) P1(1) P1(2) P1(3) P1(4) default: phase1<5>(v, hs, r, seg); }
        __syncthreads();

        float4 xv[4];
#pragma unroll
        for (int i = 0; i < 4; ++i) xv[i] = *(const float4*)(xp + (y0 + i) * W + x0);
        float4 vs4[4], pre4[4];
        switch (q) { P2(0) P2(1) P2(2) P2(3) P2(4) default: phase2<5>(hs, x0, y0, vs4, pre4); }
        dilate_store(vs4, pre4, xv, fb, fs, op, cg, x0, y0);
        __syncthreads();  // hs reads done -> plane reusable next iteration
    }
}

extern "C" void kernel_launch(void* const* d_in, const int* in_sizes, int n_in,
                              void* d_out, int out_size, void* d_ws, size_t ws_size,
                              hipStream_t stream) {
    const float* x  = (const float*)d_in[0];
    const float* w1 = (const float*)d_in[1];
    const float* b1 = (const float*)d_in[2];
    const float* w2 = (const float*)d_in[3];
    const float* b2 = (const float*)d_in[4];
    float* out = (float*)d_out;
    float* gap = (float*)d_ws;                 // NCH floats

    gap_kernel<<<NCH, 256, 0, stream>>>(x, gap);
    score_pool_kernel<<<NBLK, 256, 0, stream>>>(x, gap, w1, b1, w2, b2, out);
}